// Round 1
// baseline (216.533 us; speedup 1.0000x reference)
//
#include <hip/hip_runtime.h>
#include <stdint.h>

typedef float v4f __attribute__((ext_vector_type(4)));

#define FP8_DENOM 358.4f  // FP8_MAX(448) * SCALE_MARGIN(0.8)

// ---------- helpers ----------

__device__ __forceinline__ unsigned pack4_fp8(float a, float b, float c, float d) {
  // v_cvt_pk_fp8_f32: RNE, saturating to +-448 (values are <=358.4 by construction)
  int v = 0;
  v = __builtin_amdgcn_cvt_pk_fp8_f32(a, b, v, false);  // bytes 0,1
  v = __builtin_amdgcn_cvt_pk_fp8_f32(c, d, v, true);   // bytes 2,3
  return (unsigned)v;
}

__device__ __forceinline__ void gload_lds16(const void* g, void* l) {
  // 16B-wide async global->LDS. LDS dest must be wave-uniform base + lane*16.
  __builtin_amdgcn_global_load_lds(
      (const __attribute__((address_space(1))) uint32_t*)(uintptr_t)g,
      (__attribute__((address_space(3))) uint32_t*)(uint32_t)(uintptr_t)l,
      16, 0, 0);
}

// ---------- amax reduction ----------

__global__ void amax_kernel(const float4* __restrict__ p, int n4, unsigned* __restrict__ out) {
  float m = 0.f;
  const int stride = gridDim.x * blockDim.x;
  for (int i = blockIdx.x * blockDim.x + threadIdx.x; i < n4; i += stride) {
    float4 v = p[i];
    m = fmaxf(m, fmaxf(fmaxf(fabsf(v.x), fabsf(v.y)), fmaxf(fabsf(v.z), fabsf(v.w))));
  }
#pragma unroll
  for (int off = 32; off > 0; off >>= 1)
    m = fmaxf(m, __shfl_down(m, off, 64));
  __shared__ float red[4];
  const int lane = threadIdx.x & 63, wid = threadIdx.x >> 6;
  if (lane == 0) red[wid] = m;
  __syncthreads();
  if (threadIdx.x == 0) {
    float mm = fmaxf(fmaxf(red[0], red[1]), fmaxf(red[2], red[3]));
    atomicMax(out, __float_as_uint(mm));  // nonneg floats: uint order == value order
  }
}

// ---------- quantize fp32 -> fp8 e4m3fn codes ----------

__global__ void quant_kernel(const float4* __restrict__ in, uint4* __restrict__ outq,
                             int n16, const unsigned* __restrict__ amax, int which) {
  const float ax = __uint_as_float(amax[0]);
  const float aw = __uint_as_float(amax[1]);
  // x_scale = amax_x/358.4 ; w_scale = max(amax_x, amax_w)/358.4 (shared amax history)
  const float scale = (which == 0) ? (ax / FP8_DENOM) : (fmaxf(ax, aw) / FP8_DENOM);
  const int stride = gridDim.x * blockDim.x;
  for (int i = blockIdx.x * blockDim.x + threadIdx.x; i < n16; i += stride) {
    float4 v0 = in[4 * i + 0], v1 = in[4 * i + 1], v2 = in[4 * i + 2], v3 = in[4 * i + 3];
    uint4 r;
    // true IEEE division to match reference t/scale exactly
    r.x = pack4_fp8(v0.x / scale, v0.y / scale, v0.z / scale, v0.w / scale);
    r.y = pack4_fp8(v1.x / scale, v1.y / scale, v1.z / scale, v1.w / scale);
    r.z = pack4_fp8(v2.x / scale, v2.y / scale, v2.z / scale, v2.w / scale);
    r.w = pack4_fp8(v3.x / scale, v3.y / scale, v3.z / scale, v3.w / scale);
    outq[i] = r;
  }
}

// ---------- fp8 GEMM: C[m,n] = (sx*sw) * sum_k Aq[m,k]*Bq[n,k] + bias[n] ----------
// M=8192 N=2048 K=2048. 128x128 tile, BK=64, 4 waves, each wave 4x4 of 16x16x32 MFMA.
// LDS layout: row-major 64B rows, 16B chunks XOR-swizzled by (row>>2)&3 so the
// ds_read_b64 fragment reads spread 2 lanes/bank-pair per half-wave (conflict-free).

__global__ void __launch_bounds__(256) gemm_fp8(
    const uint8_t* __restrict__ Aq, const uint8_t* __restrict__ Bq,
    const float* __restrict__ bias, float* __restrict__ out,
    const unsigned* __restrict__ amax) {
  constexpr int K = 2048, N = 2048, BK = 64;
  __shared__ alignas(16) uint8_t sA[128 * BK];
  __shared__ alignas(16) uint8_t sB[128 * BK];

  const int tid = threadIdx.x;
  const int lane = tid & 63;
  const int wid = tid >> 6;
  const int wy = wid >> 1, wx = wid & 1;  // 2x2 waves -> 64x64 per wave
  const long tileM = (long)blockIdx.y * 128;
  const long tileN = (long)blockIdx.x * 128;

  v4f acc[4][4];
#pragma unroll
  for (int i = 0; i < 4; ++i)
#pragma unroll
    for (int j = 0; j < 4; ++j) acc[i][j] = (v4f)(0.f);

  // staging: thread t covers row sr=t/4 (chunk0: rows 0..63) and sr+64 (chunk1),
  // 16B chunk sc=t%3.. t&3, fetched from swizzled source chunk sc ^ ((sr>>2)&3).
  const int sr = tid >> 2;
  const int sc = tid & 3;
  const int scc = sc ^ ((sr >> 2) & 3);  // same swizzle for rows sr and sr+64
  const uint8_t* gA0 = Aq + (tileM + sr) * K + scc * 16;
  const uint8_t* gA1 = gA0 + 64L * K;
  const uint8_t* gB0 = Bq + (tileN + sr) * K + scc * 16;
  const uint8_t* gB1 = gB0 + 64L * K;

  const int q = lane >> 4;           // quad: k = q*8 + j
  const int mrow = lane & 15;        // row within 16x16 tile
  const int sig = (lane >> 2) & 3;   // = ((row)>>2)&3 since tile bases are x16

  for (int k0 = 0; k0 < K; k0 += BK) {
    gload_lds16(gA0 + k0, sA + tid * 16);
    gload_lds16(gA1 + k0, sA + 4096 + tid * 16);
    gload_lds16(gB0 + k0, sB + tid * 16);
    gload_lds16(gB1 + k0, sB + 4096 + tid * 16);
    __syncthreads();  // compiler emits s_waitcnt vmcnt(0) before s_barrier

    long af[2][4], bf[2][4];
#pragma unroll
    for (int s = 0; s < 2; ++s) {
      // logical byte offset in row = s*32 + q*8 -> chunk s*2+(q>>1), rem (q&1)*8
      const int phys = 16 * ((s * 2 + (q >> 1)) ^ sig) + (q & 1) * 8;
#pragma unroll
      for (int i = 0; i < 4; ++i) {
        af[s][i] = *(const long*)(sA + (wy * 64 + i * 16 + mrow) * 64 + phys);
        bf[s][i] = *(const long*)(sB + (wx * 64 + i * 16 + mrow) * 64 + phys);
      }
    }
#pragma unroll
    for (int s = 0; s < 2; ++s)
#pragma unroll
      for (int i = 0; i < 4; ++i)
#pragma unroll
        for (int j = 0; j < 4; ++j)
          acc[i][j] = __builtin_amdgcn_mfma_f32_16x16x32_fp8_fp8(af[s][i], bf[s][j],
                                                                 acc[i][j], 0, 0, 0);
    __syncthreads();
  }

  // epilogue: C/D layout col=lane&15, row=(lane>>4)*4+reg (dtype-independent, m89)
  const float ax = __uint_as_float(amax[0]);
  const float aw = __uint_as_float(amax[1]);
  const float scale = (ax / FP8_DENOM) * (fmaxf(ax, aw) / FP8_DENOM);
#pragma unroll
  for (int j = 0; j < 4; ++j) {
    const long col = tileN + wx * 64 + j * 16 + mrow;
    const float bv = bias[col];
#pragma unroll
    for (int i = 0; i < 4; ++i) {
      const long row = tileM + wy * 64 + i * 16 + q * 4;
#pragma unroll
      for (int r = 0; r < 4; ++r)
        out[(row + r) * N + col] = acc[i][j][r] * scale + bv;
    }
  }
}

// ---------- launch ----------

extern "C" void kernel_launch(void* const* d_in, const int* in_sizes, int n_in,
                              void* d_out, int out_size, void* d_ws, size_t ws_size,
                              hipStream_t stream) {
  const float* x = (const float*)d_in[0];     // [4,2048,2048] -> [8192,2048]
  const float* w = (const float*)d_in[1];     // [2048,2048]
  const float* bias = (const float*)d_in[2];  // [2048]
  float* out = (float*)d_out;                 // [8192,2048] fp32

  const int M = 8192, N = 2048, K = 2048;
  const long nx = (long)M * K, nw = (long)N * K;

  unsigned* amax = (unsigned*)d_ws;                 // 2 floats as uint bits
  uint8_t* xq = (uint8_t*)d_ws + 256;               // [M,K] fp8 codes
  uint8_t* wq = xq + nx;                            // [N,K] fp8 codes

  hipMemsetAsync(d_ws, 0, 8, stream);  // amax slots (ws is re-poisoned each call)

  amax_kernel<<<1024, 256, 0, stream>>>((const float4*)x, (int)(nx / 4), amax + 0);
  amax_kernel<<<512, 256, 0, stream>>>((const float4*)w, (int)(nw / 4), amax + 1);

  quant_kernel<<<4096, 256, 0, stream>>>((const float4*)x, (uint4*)xq, (int)(nx / 16), amax, 0);
  quant_kernel<<<1024, 256, 0, stream>>>((const float4*)w, (uint4*)wq, (int)(nw / 16), amax, 1);

  gemm_fp8<<<dim3(N / 128, M / 128), 256, 0, stream>>>(xq, wq, bias, out, amax);
}

// Round 2
// 213.681 us; speedup vs baseline: 1.0133x; 1.0133x over previous
//
#include <hip/hip_runtime.h>
#include <stdint.h>

typedef float v4f __attribute__((ext_vector_type(4)));
typedef int v8i __attribute__((ext_vector_type(8)));

#define FP8_DENOM 358.4f  // FP8_MAX(448) * SCALE_MARGIN(0.8)

// ---------- helpers ----------

__device__ __forceinline__ unsigned pack4_fp8(float a, float b, float c, float d) {
  // v_cvt_pk_fp8_f32: RNE, saturating (values <=358.4 by construction)
  int v = 0;
  v = __builtin_amdgcn_cvt_pk_fp8_f32(a, b, v, false);  // bytes 0,1
  v = __builtin_amdgcn_cvt_pk_fp8_f32(c, d, v, true);   // bytes 2,3
  return (unsigned)v;
}

__device__ __forceinline__ void gload_lds16(const void* g, void* l) {
  // 16B-wide async global->LDS. LDS dest must be wave-uniform base + lane*16.
  __builtin_amdgcn_global_load_lds(
      (const __attribute__((address_space(1))) uint32_t*)(uintptr_t)g,
      (__attribute__((address_space(3))) uint32_t*)(uint32_t)(uintptr_t)l,
      16, 0, 0);
}

// ---------- fused amax over x and w (one launch) ----------

__global__ void amax2_kernel(const float4* __restrict__ x, int nx4,
                             const float4* __restrict__ w, int nw4,
                             int xblocks, unsigned* __restrict__ out) {
  const int isw = ((int)blockIdx.x >= xblocks) ? 1 : 0;
  const float4* p = isw ? w : x;
  const int n4 = isw ? nw4 : nx4;
  const int b0 = isw ? ((int)blockIdx.x - xblocks) : (int)blockIdx.x;
  const int nb = isw ? ((int)gridDim.x - xblocks) : xblocks;
  float m = 0.f;
  const long stride = (long)nb * blockDim.x;
  for (long i = (long)b0 * blockDim.x + threadIdx.x; i < n4; i += stride) {
    float4 v = p[i];
    m = fmaxf(m, fmaxf(fmaxf(fabsf(v.x), fabsf(v.y)), fmaxf(fabsf(v.z), fabsf(v.w))));
  }
#pragma unroll
  for (int off = 32; off > 0; off >>= 1)
    m = fmaxf(m, __shfl_down(m, off, 64));
  __shared__ float red[4];
  const int lane = threadIdx.x & 63, wvid = threadIdx.x >> 6;
  if (lane == 0) red[wvid] = m;
  __syncthreads();
  if (threadIdx.x == 0) {
    float mm = fmaxf(fmaxf(red[0], red[1]), fmaxf(red[2], red[3]));
    atomicMax(out + isw, __float_as_uint(mm));  // nonneg: uint order == value order
  }
}

// ---------- fused quantize x and w -> fp8 e4m3fn codes (one launch) ----------

__global__ void quant2_kernel(const float4* __restrict__ x, uint4* __restrict__ xq, int nx16,
                              const float4* __restrict__ w, uint4* __restrict__ wq, int nw16,
                              int xblocks, const unsigned* __restrict__ amax) {
  const float ax = __uint_as_float(amax[0]);
  const float aw = __uint_as_float(amax[1]);
  const int isw = ((int)blockIdx.x >= xblocks) ? 1 : 0;
  // x_scale = amax_x/358.4 ; w_scale = max(amax_x, amax_w)/358.4 (shared history)
  const float scale = isw ? (fmaxf(ax, aw) / FP8_DENOM) : (ax / FP8_DENOM);
  const float4* in = isw ? w : x;
  uint4* outq = isw ? wq : xq;
  const int n16 = isw ? nw16 : nx16;
  const int b0 = isw ? ((int)blockIdx.x - xblocks) : (int)blockIdx.x;
  const int nb = isw ? ((int)gridDim.x - xblocks) : xblocks;
  const long stride = (long)nb * blockDim.x;
  for (long i = (long)b0 * blockDim.x + threadIdx.x; i < n16; i += stride) {
    float4 v0 = in[4 * i + 0], v1 = in[4 * i + 1], v2 = in[4 * i + 2], v3 = in[4 * i + 3];
    uint4 r;
    // true IEEE division to match reference t/scale exactly
    r.x = pack4_fp8(v0.x / scale, v0.y / scale, v0.z / scale, v0.w / scale);
    r.y = pack4_fp8(v1.x / scale, v1.y / scale, v1.z / scale, v1.w / scale);
    r.z = pack4_fp8(v2.x / scale, v2.y / scale, v2.z / scale, v2.w / scale);
    r.w = pack4_fp8(v3.x / scale, v3.y / scale, v3.z / scale, v3.w / scale);
    outq[i] = r;
  }
}

// ---------- MX-scaled fp8 GEMM: C = (sx*sw) * Aq.Bq^T + bias ----------
// M=8192 N=2048 K=2048. 128x128x128 tile, 4 waves (2x2), each wave 4x4 of
// 16x16x128 mfma_scale with unit e8m0 scales (products bit-identical to plain
// fp8 MFMA, 2x the rate — m148).
// LDS: row pitch 128B = 8 chunks of 16B; chunk XOR-swizzled by (row&7) so
// fragment ds_read_b128 lands 2 lanes/bank-group (free) and staging stays
// the wave-uniform base + lane*16 pattern global_load_lds requires.

__global__ void __launch_bounds__(256) gemm_mx(
    const uint8_t* __restrict__ Aq, const uint8_t* __restrict__ Bq,
    const float* __restrict__ bias, float* __restrict__ out,
    const unsigned* __restrict__ amax) {
  constexpr int K = 2048, N = 2048, BK = 128;
  __shared__ alignas(16) uint8_t sA[128 * BK];
  __shared__ alignas(16) uint8_t sB[128 * BK];

  const int tid = threadIdx.x;
  const int lane = tid & 63;
  const int wid = tid >> 6;
  const int wy = wid >> 1, wx = wid & 1;  // 2x2 waves -> 64x64 per wave
  const long tileM = (long)blockIdx.y * 128;
  const long tileN = (long)blockIdx.x * 128;

  v4f acc[4][4];
#pragma unroll
  for (int i = 0; i < 4; ++i)
#pragma unroll
    for (int j = 0; j < 4; ++j) acc[i][j] = (v4f)(0.f);

  // staging: thread t -> row srow = t>>3 (plus s*32 per issue), phys chunk t&7,
  // source logical chunk = (t&7) ^ (srow&7)  (row&7 invariant across s since 32%8==0)
  const int srow = tid >> 3;
  const int schunk = (tid & 7) ^ (srow & 7);
  const uint8_t* gA = Aq + (tileM + srow) * K + schunk * 16;
  const uint8_t* gB = Bq + (tileN + srow) * K + schunk * 16;

  const int q = lane >> 4;     // k-block: lane holds k = q*32 .. q*32+31
  const int mrow = lane & 15;  // row within 16x16 tile

  // fragment LDS offsets (loop-invariant): logical chunks 2q,2q+1 of row r
  int aoff[4][2], boff[4][2];
#pragma unroll
  for (int i = 0; i < 4; ++i) {
    const int rA = wy * 64 + i * 16 + mrow, swA = rA & 7;
    aoff[i][0] = rA * 128 + 16 * ((2 * q) ^ swA);
    aoff[i][1] = rA * 128 + 16 * ((2 * q + 1) ^ swA);
    const int rB = wx * 64 + i * 16 + mrow, swB = rB & 7;
    boff[i][0] = rB * 128 + 16 * ((2 * q) ^ swB);
    boff[i][1] = rB * 128 + 16 * ((2 * q + 1) ^ swB);
  }

  for (int k0 = 0; k0 < K; k0 += BK) {
#pragma unroll
    for (int s = 0; s < 4; ++s) {
      gload_lds16(gA + (long)s * 32 * K + k0, sA + s * 4096 + tid * 16);
      gload_lds16(gB + (long)s * 32 * K + k0, sB + s * 4096 + tid * 16);
    }
    __syncthreads();  // compiler emits s_waitcnt vmcnt(0) before s_barrier

    union Frag { v8i v; uint4 h[2]; };
    Frag a[4], b[4];
#pragma unroll
    for (int i = 0; i < 4; ++i) {
      a[i].h[0] = *(const uint4*)(sA + aoff[i][0]);
      a[i].h[1] = *(const uint4*)(sA + aoff[i][1]);
      b[i].h[0] = *(const uint4*)(sB + boff[i][0]);
      b[i].h[1] = *(const uint4*)(sB + boff[i][1]);
    }
#pragma unroll
    for (int i = 0; i < 4; ++i)
#pragma unroll
      for (int j = 0; j < 4; ++j)
        acc[i][j] = __builtin_amdgcn_mfma_scale_f32_16x16x128_f8f6f4(
            a[i].v, b[j].v, acc[i][j], /*cbsz=fp8*/ 0, /*blgp=fp8*/ 0,
            /*opsel_a*/ 0, 0x7F7F7F7F, /*opsel_b*/ 0, 0x7F7F7F7F);  // e8m0 127 = x1.0
    __syncthreads();
  }

  // epilogue: C/D layout col=lane&15, row=(lane>>4)*4+reg (shape-determined, m127/m128)
  const float ax = __uint_as_float(amax[0]);
  const float aw = __uint_as_float(amax[1]);
  const float scale = (ax / FP8_DENOM) * (fmaxf(ax, aw) / FP8_DENOM);
#pragma unroll
  for (int j = 0; j < 4; ++j) {
    const long col = tileN + wx * 64 + j * 16 + mrow;
    const float bv = bias[col];
#pragma unroll
    for (int i = 0; i < 4; ++i) {
      const long row = tileM + wy * 64 + i * 16 + q * 4;
#pragma unroll
      for (int r = 0; r < 4; ++r)
        out[(row + r) * N + col] = acc[i][j][r] * scale + bv;
    }
  }
}

// ---------- launch ----------

extern "C" void kernel_launch(void* const* d_in, const int* in_sizes, int n_in,
                              void* d_out, int out_size, void* d_ws, size_t ws_size,
                              hipStream_t stream) {
  const float* x = (const float*)d_in[0];     // [4,2048,2048] -> [8192,2048]
  const float* w = (const float*)d_in[1];     // [2048,2048]
  const float* bias = (const float*)d_in[2];  // [2048]
  float* out = (float*)d_out;                 // [8192,2048] fp32

  const int M = 8192, N = 2048, K = 2048;
  const long nx = (long)M * K, nw = (long)N * K;

  unsigned* amax = (unsigned*)d_ws;    // 2 floats as uint bits
  uint8_t* xq = (uint8_t*)d_ws + 256;  // [M,K] fp8 codes
  uint8_t* wq = xq + nx;               // [N,K] fp8 codes

  hipMemsetAsync(d_ws, 0, 8, stream);  // amax slots (ws re-poisoned each call)

  // x is 4x the elements of w -> split blocks ~4:1
  amax2_kernel<<<4096, 256, 0, stream>>>((const float4*)x, (int)(nx / 4),
                                         (const float4*)w, (int)(nw / 4), 3072, amax);
  quant2_kernel<<<5120, 256, 0, stream>>>((const float4*)x, (uint4*)xq, (int)(nx / 16),
                                          (const float4*)w, (uint4*)wq, (int)(nw / 16),
                                          4096, amax);
  gemm_mx<<<dim3(N / 128, M / 128), 256, 0, stream>>>(xq, wq, bias, out, amax);
}

// Round 3
// 179.639 us; speedup vs baseline: 1.2054x; 1.1895x over previous
//
#include <hip/hip_runtime.h>
#include <stdint.h>

typedef float v4f __attribute__((ext_vector_type(4)));
typedef int v8i __attribute__((ext_vector_type(8)));

#define FP8_DENOM 358.4f  // FP8_MAX(448) * SCALE_MARGIN(0.8)

// ---------- helpers ----------

__device__ __forceinline__ unsigned pack4_fp8(float a, float b, float c, float d) {
  // v_cvt_pk_fp8_f32: RNE, saturating (values <=358.4 by construction)
  int v = 0;
  v = __builtin_amdgcn_cvt_pk_fp8_f32(a, b, v, false);  // bytes 0,1
  v = __builtin_amdgcn_cvt_pk_fp8_f32(c, d, v, true);   // bytes 2,3
  return (unsigned)v;
}

__device__ __forceinline__ void gload_lds16(const void* g, void* l) {
  // 16B-wide async global->LDS. LDS dest must be wave-uniform base + lane*16.
  __builtin_amdgcn_global_load_lds(
      (const __attribute__((address_space(1))) uint32_t*)(uintptr_t)g,
      (__attribute__((address_space(3))) uint32_t*)(uint32_t)(uintptr_t)l,
      16, 0, 0);
}

// ---------- stage 1: per-block partial amax (NO atomics — they serialized r2) ----------
// blocks 0..1023 cover x (4096 float4 each), blocks 1024..1279 cover w (4096 float4 each).

__global__ void __launch_bounds__(256) amax_part(const float4* __restrict__ x,
                                                 const float4* __restrict__ w,
                                                 float* __restrict__ part) {
  const int b = blockIdx.x, t = threadIdx.x;
  const float4* p = (b < 1024) ? x : w;
  const long base = (long)((b < 1024) ? b : (b - 1024)) * 4096;
  float m0 = 0.f, m1 = 0.f, m2 = 0.f, m3 = 0.f;
#pragma unroll
  for (int j = 0; j < 4; ++j) {
    // 4 independent 16B loads in flight per iteration, fully coalesced
    float4 v0 = p[base + (j * 4 + 0) * 256 + t];
    float4 v1 = p[base + (j * 4 + 1) * 256 + t];
    float4 v2 = p[base + (j * 4 + 2) * 256 + t];
    float4 v3 = p[base + (j * 4 + 3) * 256 + t];
    m0 = fmaxf(m0, fmaxf(fmaxf(fabsf(v0.x), fabsf(v0.y)), fmaxf(fabsf(v0.z), fabsf(v0.w))));
    m1 = fmaxf(m1, fmaxf(fmaxf(fabsf(v1.x), fabsf(v1.y)), fmaxf(fabsf(v1.z), fabsf(v1.w))));
    m2 = fmaxf(m2, fmaxf(fmaxf(fabsf(v2.x), fabsf(v2.y)), fmaxf(fabsf(v2.z), fabsf(v2.w))));
    m3 = fmaxf(m3, fmaxf(fmaxf(fabsf(v3.x), fabsf(v3.y)), fmaxf(fabsf(v3.z), fabsf(v3.w))));
  }
  float m = fmaxf(fmaxf(m0, m1), fmaxf(m2, m3));
#pragma unroll
  for (int off = 32; off > 0; off >>= 1)
    m = fmaxf(m, __shfl_down(m, off, 64));
  __shared__ float red[4];
  const int lane = t & 63, wvid = t >> 6;
  if (lane == 0) red[wvid] = m;
  __syncthreads();
  if (t == 0) part[b] = fmaxf(fmaxf(red[0], red[1]), fmaxf(red[2], red[3]));
}

// ---------- stage 2: single block reduces 1280 partials -> amax[0], amax[1] ----------

__global__ void __launch_bounds__(256) scale_reduce(const float* __restrict__ part,
                                                    unsigned* __restrict__ amax) {
  const int t = threadIdx.x;
  float mx = fmaxf(fmaxf(part[t], part[t + 256]), fmaxf(part[t + 512], part[t + 768]));
  float mw = part[1024 + t];
#pragma unroll
  for (int off = 32; off > 0; off >>= 1) {
    mx = fmaxf(mx, __shfl_down(mx, off, 64));
    mw = fmaxf(mw, __shfl_down(mw, off, 64));
  }
  __shared__ float rx[4], rw[4];
  const int lane = t & 63, wvid = t >> 6;
  if (lane == 0) { rx[wvid] = mx; rw[wvid] = mw; }
  __syncthreads();
  if (t == 0) {
    amax[0] = __float_as_uint(fmaxf(fmaxf(rx[0], rx[1]), fmaxf(rx[2], rx[3])));
    amax[1] = __float_as_uint(fmaxf(fmaxf(rw[0], rw[1]), fmaxf(rw[2], rw[3])));
  }
}

// ---------- fused quantize x and w -> fp8 e4m3fn codes (one launch) ----------

__global__ void quant2_kernel(const float4* __restrict__ x, uint4* __restrict__ xq, int nx16,
                              const float4* __restrict__ w, uint4* __restrict__ wq, int nw16,
                              int xblocks, const unsigned* __restrict__ amax) {
  const float ax = __uint_as_float(amax[0]);
  const float aw = __uint_as_float(amax[1]);
  const int isw = ((int)blockIdx.x >= xblocks) ? 1 : 0;
  // x_scale = amax_x/358.4 ; w_scale = max(amax_x, amax_w)/358.4 (shared history)
  const float scale = isw ? (fmaxf(ax, aw) / FP8_DENOM) : (ax / FP8_DENOM);
  const float4* in = isw ? w : x;
  uint4* outq = isw ? wq : xq;
  const int n16 = isw ? nw16 : nx16;
  const int b0 = isw ? ((int)blockIdx.x - xblocks) : (int)blockIdx.x;
  const int nb = isw ? ((int)gridDim.x - xblocks) : xblocks;
  const long stride = (long)nb * blockDim.x;
  for (long i = (long)b0 * blockDim.x + threadIdx.x; i < n16; i += stride) {
    float4 v0 = in[4 * i + 0], v1 = in[4 * i + 1], v2 = in[4 * i + 2], v3 = in[4 * i + 3];
    uint4 r;
    // true IEEE division to match reference t/scale exactly
    r.x = pack4_fp8(v0.x / scale, v0.y / scale, v0.z / scale, v0.w / scale);
    r.y = pack4_fp8(v1.x / scale, v1.y / scale, v1.z / scale, v1.w / scale);
    r.z = pack4_fp8(v2.x / scale, v2.y / scale, v2.z / scale, v2.w / scale);
    r.w = pack4_fp8(v3.x / scale, v3.y / scale, v3.z / scale, v3.w / scale);
    outq[i] = r;
  }
}

// ---------- MX-scaled fp8 GEMM: C = (sx*sw) * Aq.Bq^T + bias ----------
// M=8192 N=2048 K=2048. 128x128x128 tile, 4 waves (2x2), each wave 4x4 of
// 16x16x128 mfma_scale with unit e8m0 scales (products bit-identical to plain
// fp8 MFMA, 2x the rate — m148).
// LDS: row pitch 128B = 8 chunks of 16B; chunk XOR-swizzled by (row&7) so
// fragment ds_read_b128 lands 2 lanes/bank-group (free) and staging stays
// the wave-uniform base + lane*16 pattern global_load_lds requires.

__global__ void __launch_bounds__(256) gemm_mx(
    const uint8_t* __restrict__ Aq, const uint8_t* __restrict__ Bq,
    const float* __restrict__ bias, float* __restrict__ out,
    const unsigned* __restrict__ amax) {
  constexpr int K = 2048, N = 2048, BK = 128;
  __shared__ alignas(16) uint8_t sA[128 * BK];
  __shared__ alignas(16) uint8_t sB[128 * BK];

  const int tid = threadIdx.x;
  const int lane = tid & 63;
  const int wid = tid >> 6;
  const int wy = wid >> 1, wx = wid & 1;  // 2x2 waves -> 64x64 per wave
  const long tileM = (long)blockIdx.y * 128;
  const long tileN = (long)blockIdx.x * 128;

  v4f acc[4][4];
#pragma unroll
  for (int i = 0; i < 4; ++i)
#pragma unroll
    for (int j = 0; j < 4; ++j) acc[i][j] = (v4f)(0.f);

  // staging: thread t -> row srow = t>>3 (plus s*32 per issue), phys chunk t&7,
  // source logical chunk = (t&7) ^ (srow&7)  (row&7 invariant across s since 32%8==0)
  const int srow = tid >> 3;
  const int schunk = (tid & 7) ^ (srow & 7);
  const uint8_t* gA = Aq + (tileM + srow) * K + schunk * 16;
  const uint8_t* gB = Bq + (tileN + srow) * K + schunk * 16;

  const int q = lane >> 4;     // k-block: lane holds k = q*32 .. q*32+31
  const int mrow = lane & 15;  // row within 16x16 tile

  // fragment LDS offsets (loop-invariant): logical chunks 2q,2q+1 of row r
  int aoff[4][2], boff[4][2];
#pragma unroll
  for (int i = 0; i < 4; ++i) {
    const int rA = wy * 64 + i * 16 + mrow, swA = rA & 7;
    aoff[i][0] = rA * 128 + 16 * ((2 * q) ^ swA);
    aoff[i][1] = rA * 128 + 16 * ((2 * q + 1) ^ swA);
    const int rB = wx * 64 + i * 16 + mrow, swB = rB & 7;
    boff[i][0] = rB * 128 + 16 * ((2 * q) ^ swB);
    boff[i][1] = rB * 128 + 16 * ((2 * q + 1) ^ swB);
  }

  for (int k0 = 0; k0 < K; k0 += BK) {
#pragma unroll
    for (int s = 0; s < 4; ++s) {
      gload_lds16(gA + (long)s * 32 * K + k0, sA + s * 4096 + tid * 16);
      gload_lds16(gB + (long)s * 32 * K + k0, sB + s * 4096 + tid * 16);
    }
    __syncthreads();  // compiler emits s_waitcnt vmcnt(0) before s_barrier

    union Frag { v8i v; uint4 h[2]; };
    Frag a[4], b[4];
#pragma unroll
    for (int i = 0; i < 4; ++i) {
      a[i].h[0] = *(const uint4*)(sA + aoff[i][0]);
      a[i].h[1] = *(const uint4*)(sA + aoff[i][1]);
      b[i].h[0] = *(const uint4*)(sB + boff[i][0]);
      b[i].h[1] = *(const uint4*)(sB + boff[i][1]);
    }
#pragma unroll
    for (int i = 0; i < 4; ++i)
#pragma unroll
      for (int j = 0; j < 4; ++j)
        acc[i][j] = __builtin_amdgcn_mfma_scale_f32_16x16x128_f8f6f4(
            a[i].v, b[j].v, acc[i][j], /*cbsz=fp8*/ 0, /*blgp=fp8*/ 0,
            /*opsel_a*/ 0, 0x7F7F7F7F, /*opsel_b*/ 0, 0x7F7F7F7F);  // e8m0 127 = x1.0
    __syncthreads();
  }

  // epilogue: C/D layout col=lane&15, row=(lane>>4)*4+reg (shape-determined, m127/m128)
  const float ax = __uint_as_float(amax[0]);
  const float aw = __uint_as_float(amax[1]);
  const float scale = (ax / FP8_DENOM) * (fmaxf(ax, aw) / FP8_DENOM);
#pragma unroll
  for (int j = 0; j < 4; ++j) {
    const long col = tileN + wx * 64 + j * 16 + mrow;
    const float bv = bias[col];
#pragma unroll
    for (int i = 0; i < 4; ++i) {
      const long row = tileM + wy * 64 + i * 16 + q * 4;
#pragma unroll
      for (int r = 0; r < 4; ++r)
        out[(row + r) * N + col] = acc[i][j][r] * scale + bv;
    }
  }
}

// ---------- launch ----------

extern "C" void kernel_launch(void* const* d_in, const int* in_sizes, int n_in,
                              void* d_out, int out_size, void* d_ws, size_t ws_size,
                              hipStream_t stream) {
  const float* x = (const float*)d_in[0];     // [4,2048,2048] -> [8192,2048]
  const float* w = (const float*)d_in[1];     // [2048,2048]
  const float* bias = (const float*)d_in[2];  // [2048]
  float* out = (float*)d_out;                 // [8192,2048] fp32

  const int M = 8192, N = 2048, K = 2048;
  const long nx = (long)M * K, nw = (long)N * K;

  // ws layout: [0,8): amax bits; [256, 256+5120): 1280 float partials;
  // [8192, 8192+nx): xq codes; then wq codes. All 16B-aligned.
  unsigned* amax = (unsigned*)d_ws;
  float* part = (float*)((uint8_t*)d_ws + 256);
  uint8_t* xq = (uint8_t*)d_ws + 8192;
  uint8_t* wq = xq + nx;

  // no memset needed: no atomics; part[] fully written by amax_part,
  // amax[] fully written by scale_reduce.
  amax_part<<<1280, 256, 0, stream>>>((const float4*)x, (const float4*)w, part);
  scale_reduce<<<1, 256, 0, stream>>>(part, amax);
  quant2_kernel<<<5120, 256, 0, stream>>>((const float4*)x, (uint4*)xq, (int)(nx / 16),
                                          (const float4*)w, (uint4*)wq, (int)(nw / 16),
                                          4096, amax);
  gemm_mx<<<dim3(N / 128, M / 128), 256, 0, stream>>>(xq, wq, bias, out, amax);
}

// Round 4
// 176.457 us; speedup vs baseline: 1.2271x; 1.0180x over previous
//
#include <hip/hip_runtime.h>
#include <stdint.h>

typedef float v4f __attribute__((ext_vector_type(4)));
typedef int v8i __attribute__((ext_vector_type(8)));

#define FP8_DENOM 358.4f  // FP8_MAX(448) * SCALE_MARGIN(0.8)

// ---------- helpers ----------

__device__ __forceinline__ unsigned pack4_fp8(float a, float b, float c, float d) {
  // v_cvt_pk_fp8_f32: RNE, saturating (values <=358.4 by construction)
  int v = 0;
  v = __builtin_amdgcn_cvt_pk_fp8_f32(a, b, v, false);  // bytes 0,1
  v = __builtin_amdgcn_cvt_pk_fp8_f32(c, d, v, true);   // bytes 2,3
  return (unsigned)v;
}

__device__ __forceinline__ void gload_lds16(const void* g, void* l) {
  // 16B-wide async global->LDS. LDS dest must be wave-uniform base + lane*16.
  __builtin_amdgcn_global_load_lds(
      (const __attribute__((address_space(1))) uint32_t*)(uintptr_t)g,
      (__attribute__((address_space(3))) uint32_t*)(uint32_t)(uintptr_t)l,
      16, 0, 0);
}

// ---------- stage 1: per-block partial amax (no atomics) ----------
// blocks 0..1023 cover x (4096 float4 each), blocks 1024..1279 cover w.

__global__ void __launch_bounds__(256) amax_part(const float4* __restrict__ x,
                                                 const float4* __restrict__ w,
                                                 float* __restrict__ part) {
  const int b = blockIdx.x, t = threadIdx.x;
  const float4* p = (b < 1024) ? x : w;
  const long base = (long)((b < 1024) ? b : (b - 1024)) * 4096;
  float m0 = 0.f, m1 = 0.f, m2 = 0.f, m3 = 0.f;
#pragma unroll
  for (int j = 0; j < 4; ++j) {
    float4 v0 = p[base + (j * 4 + 0) * 256 + t];
    float4 v1 = p[base + (j * 4 + 1) * 256 + t];
    float4 v2 = p[base + (j * 4 + 2) * 256 + t];
    float4 v3 = p[base + (j * 4 + 3) * 256 + t];
    m0 = fmaxf(m0, fmaxf(fmaxf(fabsf(v0.x), fabsf(v0.y)), fmaxf(fabsf(v0.z), fabsf(v0.w))));
    m1 = fmaxf(m1, fmaxf(fmaxf(fabsf(v1.x), fabsf(v1.y)), fmaxf(fabsf(v1.z), fabsf(v1.w))));
    m2 = fmaxf(m2, fmaxf(fmaxf(fabsf(v2.x), fabsf(v2.y)), fmaxf(fabsf(v2.z), fabsf(v2.w))));
    m3 = fmaxf(m3, fmaxf(fmaxf(fabsf(v3.x), fabsf(v3.y)), fmaxf(fabsf(v3.z), fabsf(v3.w))));
  }
  float m = fmaxf(fmaxf(m0, m1), fmaxf(m2, m3));
#pragma unroll
  for (int off = 32; off > 0; off >>= 1)
    m = fmaxf(m, __shfl_down(m, off, 64));
  __shared__ float red[4];
  const int lane = t & 63, wvid = t >> 6;
  if (lane == 0) red[wvid] = m;
  __syncthreads();
  if (t == 0) part[b] = fmaxf(fmaxf(red[0], red[1]), fmaxf(red[2], red[3]));
}

// ---------- stage 2: reduce partials; precompute scales & reciprocals ----------
// amax[0]=amax_x bits, [1]=amax_w, [2]=1/sx, [3]=1/sw, [4]=sx*sw

__global__ void __launch_bounds__(256) scale_reduce(const float* __restrict__ part,
                                                    unsigned* __restrict__ amax) {
  const int t = threadIdx.x;
  float mx = fmaxf(fmaxf(part[t], part[t + 256]), fmaxf(part[t + 512], part[t + 768]));
  float mw = part[1024 + t];
#pragma unroll
  for (int off = 32; off > 0; off >>= 1) {
    mx = fmaxf(mx, __shfl_down(mx, off, 64));
    mw = fmaxf(mw, __shfl_down(mw, off, 64));
  }
  __shared__ float rx[4], rw[4];
  const int lane = t & 63, wvid = t >> 6;
  if (lane == 0) { rx[wvid] = mx; rw[wvid] = mw; }
  __syncthreads();
  if (t == 0) {
    const float ax = fmaxf(fmaxf(rx[0], rx[1]), fmaxf(rx[2], rx[3]));
    const float aw = fmaxf(fmaxf(rw[0], rw[1]), fmaxf(rw[2], rw[3]));
    const float sx = ax / FP8_DENOM;
    const float sw = fmaxf(ax, aw) / FP8_DENOM;  // shared amax history max
    amax[0] = __float_as_uint(ax);
    amax[1] = __float_as_uint(aw);
    amax[2] = __float_as_uint(1.0f / sx);
    amax[3] = __float_as_uint(1.0f / sw);
    amax[4] = __float_as_uint(sx * sw);
  }
}

// ---------- fused quantize x and w -> fp8 e4m3fn codes ----------
// multiply by precomputed reciprocal (r3: IEEE div was ~10 VALU ops/elem)

__global__ void quant2_kernel(const float4* __restrict__ x, uint4* __restrict__ xq, int nx16,
                              const float4* __restrict__ w, uint4* __restrict__ wq, int nw16,
                              int xblocks, const unsigned* __restrict__ amax) {
  const int isw = ((int)blockIdx.x >= xblocks) ? 1 : 0;
  const float rs = __uint_as_float(amax[2 + isw]);  // 1/scale (wave-uniform)
  const float4* in = isw ? w : x;
  uint4* outq = isw ? wq : xq;
  const int n16 = isw ? nw16 : nx16;
  const int b0 = isw ? ((int)blockIdx.x - xblocks) : (int)blockIdx.x;
  const int nb = isw ? ((int)gridDim.x - xblocks) : xblocks;
  const long stride = (long)nb * blockDim.x;
  for (long i = (long)b0 * blockDim.x + threadIdx.x; i < n16; i += stride) {
    float4 v0 = in[4 * i + 0], v1 = in[4 * i + 1], v2 = in[4 * i + 2], v3 = in[4 * i + 3];
    uint4 r;
    r.x = pack4_fp8(v0.x * rs, v0.y * rs, v0.z * rs, v0.w * rs);
    r.y = pack4_fp8(v1.x * rs, v1.y * rs, v1.z * rs, v1.w * rs);
    r.z = pack4_fp8(v2.x * rs, v2.y * rs, v2.z * rs, v2.w * rs);
    r.w = pack4_fp8(v3.x * rs, v3.y * rs, v3.z * rs, v3.w * rs);
    outq[i] = r;
  }
}

// ---------- MX-scaled fp8 GEMM, double-buffered LDS ----------
// M=8192 N=2048 K=2048. 128x128x128 tile, 4 waves (2x2), 16x16x128 mfma_scale
// with unit e8m0 scales. r3 showed MfmaUtil 21%: staging latency serially
// exposed (loads issued then immediately drained by barrier). Fix: 2x32KB LDS
// buffers; iter it issues staging(it+1) right after the barrier, then runs 16
// MFMAs from buf(it) — the next barrier's vmcnt(0) drain finds loads already
// landed. One barrier per iter.

__global__ void __launch_bounds__(256) gemm_mx(
    const uint8_t* __restrict__ Aq, const uint8_t* __restrict__ Bq,
    const float* __restrict__ bias, float* __restrict__ out,
    const unsigned* __restrict__ amax) {
  constexpr int K = 2048, N = 2048, BK = 128, ITERS = K / BK;
  __shared__ alignas(16) uint8_t sA[2][128 * BK];
  __shared__ alignas(16) uint8_t sB[2][128 * BK];

  const int tid = threadIdx.x;
  const int lane = tid & 63;
  const int wid = tid >> 6;
  const int wy = wid >> 1, wx = wid & 1;  // 2x2 waves -> 64x64 per wave
  const long tileM = (long)blockIdx.y * 128;
  const long tileN = (long)blockIdx.x * 128;

  v4f acc[4][4];
#pragma unroll
  for (int i = 0; i < 4; ++i)
#pragma unroll
    for (int j = 0; j < 4; ++j) acc[i][j] = (v4f)(0.f);

  // staging: thread t -> row srow = t>>3 (+ s*32), phys chunk t&7,
  // source logical chunk = (t&7) ^ (srow&7)  (row&7 invariant across s)
  const int srow = tid >> 3;
  const int schunk = (tid & 7) ^ (srow & 7);
  const uint8_t* gA = Aq + (tileM + srow) * K + schunk * 16;
  const uint8_t* gB = Bq + (tileN + srow) * K + schunk * 16;

  const int q = lane >> 4;     // k-block: lane holds k = q*32 .. q*32+31
  const int mrow = lane & 15;  // row within 16x16 tile

  // fragment LDS offsets (loop-invariant): logical chunks 2q,2q+1 of row r
  int aoff[4][2], boff[4][2];
#pragma unroll
  for (int i = 0; i < 4; ++i) {
    const int rA = wy * 64 + i * 16 + mrow, swA = rA & 7;
    aoff[i][0] = rA * 128 + 16 * ((2 * q) ^ swA);
    aoff[i][1] = rA * 128 + 16 * ((2 * q + 1) ^ swA);
    const int rB = wx * 64 + i * 16 + mrow, swB = rB & 7;
    boff[i][0] = rB * 128 + 16 * ((2 * q) ^ swB);
    boff[i][1] = rB * 128 + 16 * ((2 * q + 1) ^ swB);
  }

  auto stage = [&](int buf, int k0) {
#pragma unroll
    for (int s = 0; s < 4; ++s) {
      gload_lds16(gA + (long)s * 32 * K + k0, &sA[buf][s * 4096 + tid * 16]);
      gload_lds16(gB + (long)s * 32 * K + k0, &sB[buf][s * 4096 + tid * 16]);
    }
  };

  stage(0, 0);
  for (int it = 0; it < ITERS; ++it) {
    __syncthreads();  // drains staging(it) — overlapped with prev iter's MFMAs
    if (it + 1 < ITERS) stage((it + 1) & 1, (it + 1) * BK);  // async prefetch

    const uint8_t* bufA = sA[it & 1];
    const uint8_t* bufB = sB[it & 1];
    union Frag { v8i v; uint4 h[2]; };
    Frag a[4], b[4];
#pragma unroll
    for (int i = 0; i < 4; ++i) {
      a[i].h[0] = *(const uint4*)(bufA + aoff[i][0]);
      a[i].h[1] = *(const uint4*)(bufA + aoff[i][1]);
      b[i].h[0] = *(const uint4*)(bufB + boff[i][0]);
      b[i].h[1] = *(const uint4*)(bufB + boff[i][1]);
    }
#pragma unroll
    for (int i = 0; i < 4; ++i)
#pragma unroll
      for (int j = 0; j < 4; ++j)
        acc[i][j] = __builtin_amdgcn_mfma_scale_f32_16x16x128_f8f6f4(
            a[i].v, b[j].v, acc[i][j], /*cbsz=fp8*/ 0, /*blgp=fp8*/ 0,
            /*opsel_a*/ 0, 0x7F7F7F7F, /*opsel_b*/ 0, 0x7F7F7F7F);  // e8m0 127 = x1.0
  }

  // epilogue: C/D layout col=lane&15, row=(lane>>4)*4+reg (shape-determined)
  const float scale = __uint_as_float(amax[4]);  // sx*sw precomputed
#pragma unroll
  for (int j = 0; j < 4; ++j) {
    const long col = tileN + wx * 64 + j * 16 + mrow;
    const float bv = bias[col];
#pragma unroll
    for (int i = 0; i < 4; ++i) {
      const long row = tileM + wy * 64 + i * 16 + q * 4;
#pragma unroll
      for (int r = 0; r < 4; ++r)
        out[(row + r) * N + col] = acc[i][j][r] * scale + bv;
    }
  }
}

// ---------- launch ----------

extern "C" void kernel_launch(void* const* d_in, const int* in_sizes, int n_in,
                              void* d_out, int out_size, void* d_ws, size_t ws_size,
                              hipStream_t stream) {
  const float* x = (const float*)d_in[0];     // [4,2048,2048] -> [8192,2048]
  const float* w = (const float*)d_in[1];     // [2048,2048]
  const float* bias = (const float*)d_in[2];  // [2048]
  float* out = (float*)d_out;                 // [8192,2048] fp32

  const int M = 8192, N = 2048, K = 2048;
  const long nx = (long)M * K, nw = (long)N * K;

  // ws layout: [0,32): amax/scale bits; [256,256+5120): 1280 float partials;
  // [8192, 8192+nx): xq codes; then wq codes. All 16B-aligned.
  unsigned* amax = (unsigned*)d_ws;
  float* part = (float*)((uint8_t*)d_ws + 256);
  uint8_t* xq = (uint8_t*)d_ws + 8192;
  uint8_t* wq = xq + nx;

  amax_part<<<1280, 256, 0, stream>>>((const float4*)x, (const float4*)w, part);
  scale_reduce<<<1, 256, 0, stream>>>(part, amax);
  quant2_kernel<<<5120, 256, 0, stream>>>((const float4*)x, (uint4*)xq, (int)(nx / 16),
                                          (const float4*)w, (uint4*)wq, (int)(nw / 16),
                                          4096, amax);
  gemm_mx<<<dim3(N / 128, M / 128), 256, 0, stream>>>(xq, wq, bias, out, amax);
}